// Round 6
// baseline (856.934 us; speedup 1.0000x reference)
//
#include <hip/hip_runtime.h>

typedef unsigned short u16;
typedef unsigned int   u32;
typedef __bf16  bf16x8 __attribute__((ext_vector_type(8)));
typedef float   f32x16 __attribute__((ext_vector_type(16)));

#define CAP      16384
#define L0_ELS   12288                    // 8 eighths x (6 chunks x 32 rows x 8)
#define HID_ELS  65536                    // 8 eighths x (32 chunks x 32 rows x 8)
#define OUT_ELS  8192                     // 32 chunks x 32 rows x 8
#define HEAD_WS  (L0_ELS + 3*HID_ELS + OUT_ELS)   // 217088 bf16 elements per head
#define HID_OFF  L0_ELS
#define OUT_OFF  (L0_ELS + 3*HID_ELS)
#define SLOT     8192                     // shorts per 16 KB ring slot

union F8 { u32 u[4]; bf16x8 v; };

__device__ __forceinline__ u16 f2b(float f) {   // fp32 -> bf16 RTNE
  u32 u = __float_as_uint(f); u += 0x7fffu + ((u >> 16) & 1u); return (u16)(u >> 16);
}
__device__ __forceinline__ u32 packbf2(float a, float b) {
  u32 ua = __float_as_uint(a); ua += 0x7fffu + ((ua >> 16) & 1u);
  u32 ub = __float_as_uint(b); ub += 0x7fffu + ((ub >> 16) & 1u);
  return (ua >> 16) | (ub & 0xffff0000u);
}
__device__ __forceinline__ f32x16 mfma16(bf16x8 a, bf16x8 b, f32x16 c) {
  return __builtin_amdgcn_mfma_f32_32x32x16_bf16(a, b, c, 0, 0, 0);
}

// ---- staging for 512 threads ----
__device__ __forceinline__ void stage_now(const u16* g, short* l, int bytes, int tid) {
  for (int base = tid * 16; base < bytes; base += 8192)
    *(uint4*)((char*)l + base) = *(const uint4*)((const char*)g + base);
}
__device__ __forceinline__ void stage_ld2(const u16* g, int bytes, int tid, uint4 st[2]) {
#pragma unroll
  for (int r = 0; r < 2; ++r) {
    const int base = tid * 16 + r * 8192;
    if (base < bytes) st[r] = *(const uint4*)((const char*)g + base);
  }
}
__device__ __forceinline__ void stage_st2(short* l, int bytes, int tid, const uint4 st[2]) {
#pragma unroll
  for (int r = 0; r < 2; ++r) {
    const int base = tid * 16 + r * 8192;
    if (base < bytes) *(uint4*)((char*)l + base) = st[r];
  }
}

// A-fragment reader, chunk-major conflict-free (R4/R5-verified: SQ_LDS_BANK_CONFLICT=0):
// 32-row slab, addr = ((c*32) + n) * 16, c = 2t+hh
__device__ __forceinline__ bf16x8 frag32(const short* sl, int t, int n, int hh) {
  return *(const bf16x8*)((const char*)sl + ((((2*t + hh) << 5) + n) << 4));
}

// D(f32x16 C-layout) -> (+bias) -> relu -> bf16 -> B-layout tiles 2e,2e+1 via lane^32 exchange
__device__ __forceinline__ void epi_core(const float cb[16], int hh, F8& t0, F8& t1) {
  u32 P[8];
#pragma unroll
  for (int i = 0; i < 8; ++i)
    P[i] = packbf2(fmaxf(cb[2*i], 0.f), fmaxf(cb[2*i+1], 0.f));
  u32 s0 = hh ? P[0] : P[2], s1 = hh ? P[1] : P[3];
  u32 s2 = hh ? P[4] : P[6], s3 = hh ? P[5] : P[7];
  u32 x0 = __shfl_xor(s0, 32, 64), x1 = __shfl_xor(s1, 32, 64);
  u32 x2 = __shfl_xor(s2, 32, 64), x3 = __shfl_xor(s3, 32, 64);
  t0.u[0] = hh ? x0 : P[0]; t0.u[1] = hh ? x1 : P[1];
  t0.u[2] = hh ? P[2] : x0; t0.u[3] = hh ? P[3] : x1;
  t1.u[0] = hh ? x2 : P[4]; t1.u[1] = hh ? x3 : P[5];
  t1.u[2] = hh ? P[6] : x2; t1.u[3] = hh ? P[7] : x3;
}
__device__ __forceinline__ void epilogue(f32x16 c, int hh, F8& t0, F8& t1) {
  float cb[16];
#pragma unroll
  for (int e = 0; e < 16; ++e) cb[e] = c[e];
  epi_core(cb, hh, t0, t1);
}
__device__ __forceinline__ void epilogueB(f32x16 c, const float4 bb[4], int hh, F8& t0, F8& t1) {
  float cb[16];
#pragma unroll
  for (int e = 0; e < 16; ++e) cb[e] = c[e] + ((const float*)bb)[e];
  epi_core(cb, hh, t0, t1);
}

// ---------------- prep (single launch): W_hid transpose + small images + coords copy ----------------
// blocks [0,768): hid transpose; [768,928): L0/OUT images; [928,1440): coords passthrough
__global__ void prep(const float* __restrict__ W_in, const float* __restrict__ b_in,
                     const float* __restrict__ W_hid, const float* __restrict__ W_out,
                     u16* __restrict__ ws,
                     const uint4* __restrict__ csrc, uint4* __restrict__ cdst) {
  __shared__ u16 tile[64 * 72];
  const int t = threadIdx.x;
  if (blockIdx.x < 768) {                              // --- hid transpose (R4-verified core) ---
    const int b = blockIdx.x;
    const int kband = b & 3, q = (b >> 2) & 3, l = (b >> 4) % 3, head = b / 48;
    const int kl = t >> 2, rg = t & 3;                 // 4 threads per k-row, 16 rows each
    const float* src = W_hid + (((head*3 + l)*256 + kband*64 + kl) << 8) + q*64 + rg*16;
    u16* dt = &tile[kl*72 + rg*16];
#pragma unroll
    for (int m = 0; m < 4; ++m) {
      float4 v = *(const float4*)(src + m*4);
      ushort4 o; o.x = f2b(v.x); o.y = f2b(v.y); o.z = f2b(v.z); o.w = f2b(v.w);
      *(ushort4*)(dt + m*4) = o;
    }
    __syncthreads();
    u16* lbase = ws + head*HEAD_WS + HID_OFF + l*HID_ELS;
#pragma unroll
    for (int p = 0; p < 2; ++p) {
      const int idx = t + p*256;                        // [0,512): cl = idx>>6, rq = idx&63
      const int cl = idx >> 6, rq = idx & 63;
      const int e = (q << 1) | (rq >> 5), r32 = rq & 31, kc = kband*8 + cl;
      u16 v8[8];
#pragma unroll
      for (int j = 0; j < 8; ++j) v8[j] = tile[(cl*8 + j)*72 + rq];
      uint4 o;
      o.x = (u32)v8[0] | ((u32)v8[1] << 16); o.y = (u32)v8[2] | ((u32)v8[3] << 16);
      o.z = (u32)v8[4] | ((u32)v8[5] << 16); o.w = (u32)v8[6] | ((u32)v8[7] << 16);
      *(uint4*)(lbase + e*SLOT + ((kc << 5) + r32) * 8) = o;   // eighth-image chunk-major
    }
    return;
  }
  if (blockIdx.x >= 928) {                             // --- coords passthrough ---
    const int i = (blockIdx.x - 928) * 256 + t;        // 512 x 256 = 131072 uint4
    cdst[i] = csrc[i];
    return;
  }
  // --- L0 (bias folded) + OUT images ---
  const int r = (blockIdx.x - 768) * 256 + t;
  const int head = r / 2560, f = r % 2560;
  u16 v[8]; int dst;
  if (f < 1536) {                                      // L0: eighth e, chunk c (0..5), row32
    const int e = f / 192, g = f % 192;
    const int c = g >> 5, row = g & 31, nn = e*32 + row, k0 = c*8;
#pragma unroll
    for (int j = 0; j < 8; ++j) {
      const int k = k0 + j;
      v[j] = (k < 40) ? f2b(W_in[head*10240 + (k << 8) + nn])
           : (k == 40) ? f2b(b_in[(head << 8) + nn]) : (u16)0;
    }
    dst = head*HEAD_WS + e*1536 + g*8;
  } else {                                             // OUT: 32 chunks x 32 rows
    const int f2 = f - 1536;
    const int c = f2 >> 5, nn = f2 & 31, k0 = c*8;
#pragma unroll
    for (int j = 0; j < 8; ++j)
      v[j] = (nn < 3) ? f2b(W_out[head*768 + (k0 + j)*3 + nn]) : (u16)0;
    dst = head*HEAD_WS + OUT_OFF + f2*8;
  }
  uint4 o;
  o.x = (u32)v[0] | ((u32)v[1] << 16); o.y = (u32)v[2] | ((u32)v[3] << 16);
  o.z = (u32)v[4] | ((u32)v[5] << 16); o.w = (u32)v[6] | ((u32)v[7] << 16);
  *(uint4*)(ws + dst) = o;
}

// ---------------- main fused MLP: 512 thr (8 waves), 32 pts/wave, 2x16KB ring ----------------
__launch_bounds__(512, 8)
__global__ void mlp_main(const float* __restrict__ coords, const int* __restrict__ head_idx,
                         const float* __restrict__ b_hid, const float* __restrict__ b_out,
                         const u16* __restrict__ ws, float* __restrict__ out) {
  __shared__ short ring[2 * SLOT];                     // 32 KB total -> 4 blocks/CU (thread-capped)
  const int tid = threadIdx.x;
  const int lane = tid & 63, wv = tid >> 6;
  const int n = lane & 31, hh = lane >> 5;
  const int head = blockIdx.x & 15, chunk = blockIdx.x >> 4;
  const u16* wsh = ws + head * HEAD_WS;
  const u16* hb  = wsh + HID_OFF;

  stage_now(wsh + 0*1536, ring,        3072, tid);     // L0 e0 -> slot0
  stage_now(wsh + 1*1536, ring + SLOT, 3072, tid);     // L0 e1 -> slot1

  // gather + positional encoding (B-layout: lane = point, k = 16t + 8*hh + j)
  const int pt = chunk*256 + wv*32 + n;
  const int g  = head_idx[head*CAP + pt];
  const float2 cxy = *(const float2*)(coords + 2*g);
  const float xs = cxy.x, ys = cxy.y;
  const float bo0 = b_out[head*3+0], bo1 = b_out[head*3+1], bo2 = b_out[head*3+2];

  F8 pe[3];
#pragma unroll
  for (int t = 0; t < 3; ++t) {
    float e[8];
#pragma unroll
    for (int half = 0; half < 2; ++half) {
      const int l = 4*t + 2*hh + half;                 // k = 4l + comp: sinx,siny,cosx,cosy
      if (l < 10) {
        const float fr = 3.14159265358979323846f * (float)(1 << l);
        float s1, c1, s2, c2;
        sincosf(xs * fr, &s1, &c1);
        sincosf(ys * fr, &s2, &c2);
        e[4*half+0] = s1; e[4*half+1] = s2; e[4*half+2] = c1; e[4*half+3] = c2;
      } else {
        e[4*half+0] = (l == 10) ? 1.0f : 0.0f;         // k=40 -> folded bias channel
        e[4*half+1] = 0.f; e[4*half+2] = 0.f; e[4*half+3] = 0.f;
      }
    }
    pe[t].u[0] = packbf2(e[0], e[1]); pe[t].u[1] = packbf2(e[2], e[3]);
    pe[t].u[2] = packbf2(e[4], e[5]); pe[t].u[3] = packbf2(e[6], e[7]);
  }

  F8 act0[16], act1[16];
  __syncthreads();                                     // L0 e0/e1 staged

  // ===== layer 0: pe -> act0 (K=48, bias folded), 8 eighth-phases =====
#pragma unroll
  for (int e = 0; e < 8; ++e) {
    short* sl = ring + (e & 1) * SLOT;
    f32x16 acc = (f32x16)0.f;
#pragma unroll
    for (int t = 0; t < 3; ++t)
      acc = mfma16(frag32(sl, t, n, hh), pe[t].v, acc);
    __syncthreads();
    const u16* src = (e < 6) ? (wsh + (e + 2)*1536) : (hb + (e - 6)*SLOT);
    const int bytes = (e < 6) ? 3072 : 16384;
    uint4 st[2];
    stage_ld2(src, bytes, tid, st);                    // issue loads early
    epilogue(acc, hh, act0[2*e], act0[2*e+1]);
    stage_st2(sl, bytes, tid, st);                     // drained by next barrier
  }

  // ===== hidden layers: 8 eighth-phases each =====
  auto hid_layer = [&](const float* bias, F8 (&ain)[16], F8 (&aout)[16],
                       const u16* lay, const u16* n0, const u16* n1, int nb7) {
#pragma unroll
    for (int e = 0; e < 8; ++e) {
      short* sl = ring + (e & 1) * SLOT;
      f32x16 acc = (f32x16)0.f;
#pragma unroll
      for (int t = 0; t < 16; ++t)
        acc = mfma16(frag32(sl, t, n, hh), ain[t].v, acc);
      __syncthreads();
      const u16* src = (e < 6) ? (lay + (e + 2)*SLOT) : (e == 6 ? n0 : n1);
      const int bytes = (e < 7) ? 16384 : nb7;
      uint4 st[2];
      if (bytes) stage_ld2(src, bytes, tid, st);
      float4 bb[4];                                    // rows 32e + 8g2 + 4hh + [0..3]
#pragma unroll
      for (int g2 = 0; g2 < 4; ++g2)
        bb[g2] = *(const float4*)(bias + 32*e + 8*g2 + 4*hh);
      epilogueB(acc, bb, hh, aout[2*e], aout[2*e+1]);
      if (bytes) stage_st2(sl, bytes, tid, st);
    }
  };

  hid_layer(b_hid + (head*3+0)*256, act0, act1, hb,
            hb + HID_ELS, hb + HID_ELS + SLOT, 16384);
  hid_layer(b_hid + (head*3+1)*256, act1, act0, hb + HID_ELS,
            hb + 2*HID_ELS, hb + 2*HID_ELS + SLOT, 16384);
  hid_layer(b_hid + (head*3+2)*256, act0, act1, hb + 2*HID_ELS,
            wsh + OUT_OFF, (const u16*)0, 0);          // e6 stages OUT image into slot0

  // ===== out layer: act1 x W_out^T (32-row image in slot0), scatter =====
  f32x16 acc = (f32x16)0.f;
#pragma unroll
  for (int t = 0; t < 16; ++t)
    acc = mfma16(frag32(ring, t, n, hh), act1[t].v, acc);
  if (hh == 0) {                                       // rows 0..2 live in hh=0 regs 0..2
    const long base = (long)g * 3;
    out[base + 0] = acc[0] + bo0;
    out[base + 1] = acc[1] + bo1;
    out[base + 2] = acc[2] + bo2;
  }
}

extern "C" void kernel_launch(void* const* d_in, const int* in_sizes, int n_in,
                              void* d_out, int out_size, void* d_ws, size_t ws_size,
                              hipStream_t stream) {
  const float* coords   = (const float*)d_in[0];
  const int*   head_idx = (const int*)d_in[1];
  const float* W_in     = (const float*)d_in[2];
  const float* b_in     = (const float*)d_in[3];
  const float* W_hid    = (const float*)d_in[4];
  const float* b_hid    = (const float*)d_in[5];
  const float* W_out    = (const float*)d_in[6];
  const float* b_out    = (const float*)d_in[7];
  float* out = (float*)d_out;
  u16*   ws  = (u16*)d_ws;
  if (ws_size < (size_t)HEAD_WS * 16 * sizeof(u16)) return;

  prep<<<dim3(1440), dim3(256), 0, stream>>>(W_in, b_in, W_hid, W_out, ws,
                                             (const uint4*)coords, (uint4*)(out + 786432));
  mlp_main<<<dim3(1024), dim3(512), 0, stream>>>(coords, head_idx, b_hid, b_out, ws, out);
}

// Round 7
// 338.025 us; speedup vs baseline: 2.5351x; 2.5351x over previous
//
#include <hip/hip_runtime.h>
#include <hip/hip_bf16.h>

typedef unsigned short u16;
typedef unsigned int   u32;
typedef __bf16  bf16x8 __attribute__((ext_vector_type(8)));
typedef float   f32x16 __attribute__((ext_vector_type(16)));

#define CAP      16384
#define L0_ELS   12288                    // 8 eighths x (6 chunks x 32 rows x 8)
#define HID_ELS  65536                    // 8 eighths x (32 chunks x 32 rows x 8)
#define OUT_ELS  8192                     // 32 chunks x 32 rows x 8
#define HEAD_WS  (L0_ELS + 3*HID_ELS + OUT_ELS)   // 217088 bf16 elements per head
#define HID_OFF  L0_ELS
#define OUT_OFF  (L0_ELS + 3*HID_ELS)
#define SLOT     8192                     // shorts per 16 KB ring slot

union F8 { u32 u[4]; bf16x8 v; };

__device__ __forceinline__ u16 f2b(float f) {   // fp32 -> bf16 RTNE
  u32 u = __float_as_uint(f); u += 0x7fffu + ((u >> 16) & 1u); return (u16)(u >> 16);
}
__device__ __forceinline__ u32 packbf2(float a, float b) {  // RTNE pair (HW pk cvt if available)
  __hip_bfloat162 h = __float22bfloat162_rn(make_float2(a, b));
  return *(u32*)&h;
}
__device__ __forceinline__ f32x16 mfma16(bf16x8 a, bf16x8 b, f32x16 c) {
  return __builtin_amdgcn_mfma_f32_32x32x16_bf16(a, b, c, 0, 0, 0);
}

// ---- staging for 256 threads ----
__device__ __forceinline__ void stage_now(const u16* g, short* l, int bytes, int tid) {
  for (int base = tid * 16; base < bytes; base += 4096)
    *(uint4*)((char*)l + base) = *(const uint4*)((const char*)g + base);
}
__device__ __forceinline__ void stage_ld4(const u16* g, int bytes, int tid, uint4 st[4]) {
#pragma unroll
  for (int r = 0; r < 4; ++r) {
    const int base = tid * 16 + r * 4096;
    if (base < bytes) st[r] = *(const uint4*)((const char*)g + base);
  }
}
__device__ __forceinline__ void stage_st4(short* l, int bytes, int tid, const uint4 st[4]) {
#pragma unroll
  for (int r = 0; r < 4; ++r) {
    const int base = tid * 16 + r * 4096;
    if (base < bytes) *(uint4*)((char*)l + base) = st[r];
  }
}

// A-fragment reader, chunk-major conflict-free (R4/R5-verified: SQ_LDS_BANK_CONFLICT=0):
// 32-row slab, addr = ((c*32) + n) * 16, c = 2t+hh
__device__ __forceinline__ bf16x8 frag32(const short* sl, int t, int n, int hh) {
  return *(const bf16x8*)((const char*)sl + ((((2*t + hh) << 5) + n) << 4));
}

// D(f32x16 C-layout) -> (+bias) -> relu -> bf16 -> B-layout tiles 2e,2e+1 via lane^32 exchange
__device__ __forceinline__ void epi_core(const float cb[16], int hh, F8& t0, F8& t1) {
  u32 P[8];
#pragma unroll
  for (int i = 0; i < 8; ++i)
    P[i] = packbf2(fmaxf(cb[2*i], 0.f), fmaxf(cb[2*i+1], 0.f));
  u32 s0 = hh ? P[0] : P[2], s1 = hh ? P[1] : P[3];
  u32 s2 = hh ? P[4] : P[6], s3 = hh ? P[5] : P[7];
  u32 x0 = __shfl_xor(s0, 32, 64), x1 = __shfl_xor(s1, 32, 64);
  u32 x2 = __shfl_xor(s2, 32, 64), x3 = __shfl_xor(s3, 32, 64);
  t0.u[0] = hh ? x0 : P[0]; t0.u[1] = hh ? x1 : P[1];
  t0.u[2] = hh ? P[2] : x0; t0.u[3] = hh ? P[3] : x1;
  t1.u[0] = hh ? x2 : P[4]; t1.u[1] = hh ? x3 : P[5];
  t1.u[2] = hh ? P[6] : x2; t1.u[3] = hh ? P[7] : x3;
}
__device__ __forceinline__ void epilogue(f32x16 c, int hh, F8& t0, F8& t1) {
  float cb[16];
#pragma unroll
  for (int e = 0; e < 16; ++e) cb[e] = c[e];
  epi_core(cb, hh, t0, t1);
}
__device__ __forceinline__ void epilogueB(f32x16 c, const float4 bb[4], int hh, F8& t0, F8& t1) {
  float cb[16];
#pragma unroll
  for (int e = 0; e < 16; ++e) cb[e] = c[e] + ((const float*)bb)[e];
  epi_core(cb, hh, t0, t1);
}

// ---------------- prep (single launch, R6-verified): W_hid transpose + small images + coords ----------------
// blocks [0,768): hid transpose; [768,928): L0/OUT images; [928,1440): coords passthrough
__global__ void prep(const float* __restrict__ W_in, const float* __restrict__ b_in,
                     const float* __restrict__ W_hid, const float* __restrict__ W_out,
                     u16* __restrict__ ws,
                     const uint4* __restrict__ csrc, uint4* __restrict__ cdst) {
  __shared__ u16 tile[64 * 72];
  const int t = threadIdx.x;
  if (blockIdx.x < 768) {                              // --- hid transpose ---
    const int b = blockIdx.x;
    const int kband = b & 3, q = (b >> 2) & 3, l = (b >> 4) % 3, head = b / 48;
    const int kl = t >> 2, rg = t & 3;                 // 4 threads per k-row, 16 rows each
    const float* src = W_hid + (((head*3 + l)*256 + kband*64 + kl) << 8) + q*64 + rg*16;
    u16* dt = &tile[kl*72 + rg*16];
#pragma unroll
    for (int m = 0; m < 4; ++m) {
      float4 v = *(const float4*)(src + m*4);
      ushort4 o; o.x = f2b(v.x); o.y = f2b(v.y); o.z = f2b(v.z); o.w = f2b(v.w);
      *(ushort4*)(dt + m*4) = o;
    }
    __syncthreads();
    u16* lbase = ws + head*HEAD_WS + HID_OFF + l*HID_ELS;
#pragma unroll
    for (int p = 0; p < 2; ++p) {
      const int idx = t + p*256;                        // [0,512): cl = idx>>6, rq = idx&63
      const int cl = idx >> 6, rq = idx & 63;
      const int e = (q << 1) | (rq >> 5), r32 = rq & 31, kc = kband*8 + cl;
      u16 v8[8];
#pragma unroll
      for (int j = 0; j < 8; ++j) v8[j] = tile[(cl*8 + j)*72 + rq];
      uint4 o;
      o.x = (u32)v8[0] | ((u32)v8[1] << 16); o.y = (u32)v8[2] | ((u32)v8[3] << 16);
      o.z = (u32)v8[4] | ((u32)v8[5] << 16); o.w = (u32)v8[6] | ((u32)v8[7] << 16);
      *(uint4*)(lbase + e*SLOT + ((kc << 5) + r32) * 8) = o;   // eighth-image chunk-major
    }
    return;
  }
  if (blockIdx.x >= 928) {                             // --- coords passthrough ---
    const int i = (blockIdx.x - 928) * 256 + t;        // 512 x 256 = 131072 uint4
    cdst[i] = csrc[i];
    return;
  }
  // --- L0 (bias folded) + OUT images ---
  const int r = (blockIdx.x - 768) * 256 + t;
  const int head = r / 2560, f = r % 2560;
  u16 v[8]; int dst;
  if (f < 1536) {                                      // L0: eighth e, chunk c (0..5), row32
    const int e = f / 192, g = f % 192;
    const int c = g >> 5, row = g & 31, nn = e*32 + row, k0 = c*8;
#pragma unroll
    for (int j = 0; j < 8; ++j) {
      const int k = k0 + j;
      v[j] = (k < 40) ? f2b(W_in[head*10240 + (k << 8) + nn])
           : (k == 40) ? f2b(b_in[(head << 8) + nn]) : (u16)0;
    }
    dst = head*HEAD_WS + e*1536 + g*8;
  } else {                                             // OUT: 32 chunks x 32 rows
    const int f2 = f - 1536;
    const int c = f2 >> 5, nn = f2 & 31, k0 = c*8;
#pragma unroll
    for (int j = 0; j < 8; ++j)
      v[j] = (nn < 3) ? f2b(W_out[head*768 + (k0 + j)*3 + nn]) : (u16)0;
    dst = head*HEAD_WS + OUT_OFF + f2*8;
  }
  uint4 o;
  o.x = (u32)v[0] | ((u32)v[1] << 16); o.y = (u32)v[2] | ((u32)v[3] << 16);
  o.z = (u32)v[4] | ((u32)v[5] << 16); o.w = (u32)v[6] | ((u32)v[7] << 16);
  *(uint4*)(ws + dst) = o;
}

// ---------------- main fused MLP: 256 thr (4 waves), 32 pts/wave, 2x16KB ring ----------------
// 2 independent blocks/CU (reg-limited 2 waves/EU) -> two barrier domains interleave
__launch_bounds__(256, 2)
__global__ void mlp_main(const float* __restrict__ coords, const int* __restrict__ head_idx,
                         const float* __restrict__ b_hid, const float* __restrict__ b_out,
                         const u16* __restrict__ ws, float* __restrict__ out) {
  __shared__ short ring[2 * SLOT];                     // 32 KB
  const int tid = threadIdx.x;
  const int lane = tid & 63, wv = tid >> 6;
  const int n = lane & 31, hh = lane >> 5;
  const int head = blockIdx.x & 15, chunk = blockIdx.x >> 4;   // 128 chunks x 128 pts
  const u16* wsh = ws + head * HEAD_WS;
  const u16* hb  = wsh + HID_OFF;

  stage_now(wsh + 0*1536, ring,        3072, tid);     // L0 e0 -> slot0
  stage_now(wsh + 1*1536, ring + SLOT, 3072, tid);     // L0 e1 -> slot1

  // gather + positional encoding (B-layout: lane = point, k = 16t + 8*hh + j)
  const int pt = chunk*128 + wv*32 + n;
  const int g  = head_idx[head*CAP + pt];
  const float2 cxy = *(const float2*)(coords + 2*g);
  const float xs = cxy.x, ys = cxy.y;
  const float bo0 = b_out[head*3+0], bo1 = b_out[head*3+1], bo2 = b_out[head*3+2];

  F8 pe[3];
#pragma unroll
  for (int t = 0; t < 3; ++t) {
    float e[8];
#pragma unroll
    for (int half = 0; half < 2; ++half) {
      const int l = 4*t + 2*hh + half;                 // k = 4l + comp: sinx,siny,cosx,cosy
      if (l < 10) {
        const float fr = 3.14159265358979323846f * (float)(1 << l);
        float s1, c1, s2, c2;
        sincosf(xs * fr, &s1, &c1);
        sincosf(ys * fr, &s2, &c2);
        e[4*half+0] = s1; e[4*half+1] = s2; e[4*half+2] = c1; e[4*half+3] = c2;
      } else {
        e[4*half+0] = (l == 10) ? 1.0f : 0.0f;         // k=40 -> folded bias channel
        e[4*half+1] = 0.f; e[4*half+2] = 0.f; e[4*half+3] = 0.f;
      }
    }
    pe[t].u[0] = packbf2(e[0], e[1]); pe[t].u[1] = packbf2(e[2], e[3]);
    pe[t].u[2] = packbf2(e[4], e[5]); pe[t].u[3] = packbf2(e[6], e[7]);
  }

  F8 act0[16], act1[16];
  __syncthreads();                                     // L0 e0/e1 staged

  // ===== layer 0: pe -> act0 (K=48, bias folded), 8 eighth-phases =====
#pragma unroll
  for (int e = 0; e < 8; ++e) {
    short* sl = ring + (e & 1) * SLOT;
    f32x16 acc = (f32x16)0.f;
#pragma unroll
    for (int t = 0; t < 3; ++t)
      acc = mfma16(frag32(sl, t, n, hh), pe[t].v, acc);
    __syncthreads();
    const u16* src = (e < 6) ? (wsh + (e + 2)*1536) : (hb + (e - 6)*SLOT);
    const int bytes = (e < 6) ? 3072 : 16384;
    uint4 st[4];
    stage_ld4(src, bytes, tid, st);                    // issue loads early
    epilogue(acc, hh, act0[2*e], act0[2*e+1]);
    stage_st4(sl, bytes, tid, st);                     // drained by next barrier
  }

  // ===== hidden layers: 8 eighth-phases each =====
  auto hid_layer = [&](const float* bias, F8 (&ain)[16], F8 (&aout)[16],
                       const u16* lay, const u16* n0, const u16* n1, int nb7) {
#pragma unroll
    for (int e = 0; e < 8; ++e) {
      short* sl = ring + (e & 1) * SLOT;
      f32x16 acc = (f32x16)0.f;
#pragma unroll
      for (int t = 0; t < 16; ++t)
        acc = mfma16(frag32(sl, t, n, hh), ain[t].v, acc);
      __syncthreads();
      const u16* src = (e < 6) ? (lay + (e + 2)*SLOT) : (e == 6 ? n0 : n1);
      const int bytes = (e < 7) ? 16384 : nb7;
      uint4 st[4];
      if (bytes) stage_ld4(src, bytes, tid, st);
      float4 bb[4];                                    // rows 32e + 8g2 + 4hh + [0..3]
#pragma unroll
      for (int g2 = 0; g2 < 4; ++g2)
        bb[g2] = *(const float4*)(bias + 32*e + 8*g2 + 4*hh);
      epilogueB(acc, bb, hh, aout[2*e], aout[2*e+1]);
      if (bytes) stage_st4(sl, bytes, tid, st);
    }
  };

  hid_layer(b_hid + (head*3+0)*256, act0, act1, hb,
            hb + HID_ELS, hb + HID_ELS + SLOT, 16384);
  hid_layer(b_hid + (head*3+1)*256, act1, act0, hb + HID_ELS,
            hb + 2*HID_ELS, hb + 2*HID_ELS + SLOT, 16384);
  hid_layer(b_hid + (head*3+2)*256, act0, act1, hb + 2*HID_ELS,
            wsh + OUT_OFF, (const u16*)0, 0);          // e6 stages OUT image into slot0

  // ===== out layer: act1 x W_out^T (32-row image in slot0), scatter =====
  f32x16 acc = (f32x16)0.f;
#pragma unroll
  for (int t = 0; t < 16; ++t)
    acc = mfma16(frag32(ring, t, n, hh), act1[t].v, acc);
  if (hh == 0) {                                       // rows 0..2 live in hh=0 regs 0..2
    const long base = (long)g * 3;
    out[base + 0] = acc[0] + bo0;
    out[base + 1] = acc[1] + bo1;
    out[base + 2] = acc[2] + bo2;
  }
}

extern "C" void kernel_launch(void* const* d_in, const int* in_sizes, int n_in,
                              void* d_out, int out_size, void* d_ws, size_t ws_size,
                              hipStream_t stream) {
  const float* coords   = (const float*)d_in[0];
  const int*   head_idx = (const int*)d_in[1];
  const float* W_in     = (const float*)d_in[2];
  const float* b_in     = (const float*)d_in[3];
  const float* W_hid    = (const float*)d_in[4];
  const float* b_hid    = (const float*)d_in[5];
  const float* W_out    = (const float*)d_in[6];
  const float* b_out    = (const float*)d_in[7];
  float* out = (float*)d_out;
  u16*   ws  = (u16*)d_ws;
  if (ws_size < (size_t)HEAD_WS * 16 * sizeof(u16)) return;

  prep<<<dim3(1440), dim3(256), 0, stream>>>(W_in, b_in, W_hid, W_out, ws,
                                             (const uint4*)coords, (uint4*)(out + 786432));
  mlp_main<<<dim3(2048), dim3(256), 0, stream>>>(coords, head_idx, b_hid, b_out, ws, out);
}

// Round 8
// 266.005 us; speedup vs baseline: 3.2215x; 1.2707x over previous
//
#include <hip/hip_runtime.h>
#include <hip/hip_bf16.h>

typedef unsigned short u16;
typedef unsigned int   u32;
typedef __bf16  bf16x8 __attribute__((ext_vector_type(8)));
typedef float   f32x16 __attribute__((ext_vector_type(16)));

#define CAP      16384
#define L0_ELS   (256*56)                 // W_in^T image: 256 rows x 56 (40 W + bias@40 + pad)
#define HID_ELS  65536                    // 256 rows x 256, XOR-swizzled chunks
#define OUT_ELS  8192                     // 32 rows x 256
#define HEAD_WS  (L0_ELS + 3*HID_ELS + OUT_ELS)   // 219136 bf16 elements per head
#define HID_OFF  L0_ELS
#define OUT_OFF  (L0_ELS + 3*HID_ELS)

union F8 { u32 u[4]; bf16x8 v; };

__device__ __forceinline__ u16 f2b(float f) {   // fp32 -> bf16 RTNE
  u32 u = __float_as_uint(f); u += 0x7fffu + ((u >> 16) & 1u); return (u16)(u >> 16);
}
__device__ __forceinline__ u32 packbf2(float a, float b) {  // HW v_cvt_pk_bf16_f32 if available
  __hip_bfloat162 h = __float22bfloat162_rn(make_float2(a, b));
  return *(u32*)&h;
}
__device__ __forceinline__ f32x16 mfma16(bf16x8 a, bf16x8 b, f32x16 c) {
  return __builtin_amdgcn_mfma_f32_32x32x16_bf16(a, b, c, 0, 0, 0);
}

// ---- staging for 512 threads: uint4 loads -> regs -> ds_write_b128 ----
__device__ __forceinline__ void stage_now(const u16* g, short* l, int bytes, int tid) {
  for (int base = tid * 16; base < bytes; base += 8192)
    *(uint4*)((char*)l + base) = *(const uint4*)((const char*)g + base);
}
__device__ __forceinline__ void stage_ld(const u16* g, int bytes, int tid, uint4 st[4]) {
#pragma unroll
  for (int r = 0; r < 4; ++r) {
    const int base = tid * 16 + r * 8192;
    if (base < bytes) st[r] = *(const uint4*)((const char*)g + base);
  }
}
__device__ __forceinline__ void stage_st(short* l, int bytes, int tid, const uint4 st[4]) {
#pragma unroll
  for (int r = 0; r < 4; ++r) {
    const int base = tid * 16 + r * 8192;
    if (base < bytes) *(uint4*)((char*)l + base) = st[r];
  }
}

// A-fragment readers (R3 layout, empirically fastest). i = row-half within 64-row quarter.
__device__ __forceinline__ bf16x8 fragL0(const short* sl, int i, int t, int n, int hh) {
  return *(const bf16x8*)((const char*)sl + (32*i + n)*112 + (2*t + hh)*16);   // 7-chunk rows
}
__device__ __forceinline__ bf16x8 fragH(const short* sl, int i, int t, int n, int hh) {
  return *(const bf16x8*)((const char*)sl + ((32*i + n) << 9) + (((2*t + hh) ^ (n & 7)) << 4)); // XOR-swizzled
}

__device__ __forceinline__ void load_bias_raw(const float* b, int r, int hh, float4 o[4]) {
#pragma unroll
  for (int g = 0; g < 4; ++g) o[g] = *(const float4*)(b + 32*r + 8*g + 4*hh);
}
__device__ __forceinline__ f32x16 bias_to_acc(const float4 raw[4]) {
  f32x16 a;
#pragma unroll
  for (int g = 0; g < 4; ++g) {
    a[4*g+0] = raw[g].x; a[4*g+1] = raw[g].y;
    a[4*g+2] = raw[g].z; a[4*g+3] = raw[g].w;
  }
  return a;
}

// D(f32x16 C-layout) -> relu -> bf16 -> B-layout tiles 2r,2r+1 via lane^32 exchange
__device__ __forceinline__ void epilogue(f32x16 c, int hh, F8& t0, F8& t1) {
  u32 P[8];
#pragma unroll
  for (int i = 0; i < 8; ++i)
    P[i] = packbf2(fmaxf(c[2*i], 0.f), fmaxf(c[2*i+1], 0.f));
  u32 s0 = hh ? P[0] : P[2], s1 = hh ? P[1] : P[3];
  u32 s2 = hh ? P[4] : P[6], s3 = hh ? P[5] : P[7];
  u32 x0 = __shfl_xor(s0, 32, 64), x1 = __shfl_xor(s1, 32, 64);
  u32 x2 = __shfl_xor(s2, 32, 64), x3 = __shfl_xor(s3, 32, 64);
  t0.u[0] = hh ? x0 : P[0]; t0.u[1] = hh ? x1 : P[1];
  t0.u[2] = hh ? P[2] : x0; t0.u[3] = hh ? P[3] : x1;
  t1.u[0] = hh ? x2 : P[4]; t1.u[1] = hh ? x3 : P[5];
  t1.u[2] = hh ? P[6] : x2; t1.u[3] = hh ? P[7] : x3;
}

// ---------------- merged prep (single launch) ----------------
// [0,768): W_hid LDS-transpose -> XOR-swizzled images; [768,944): L0+OUT; [944,1456): coords copy
__global__ void prep(const float* __restrict__ W_in, const float* __restrict__ b_in,
                     const float* __restrict__ W_hid, const float* __restrict__ b_in_unused,
                     const float* __restrict__ W_out, u16* __restrict__ ws,
                     const uint4* __restrict__ csrc, uint4* __restrict__ cdst) {
  __shared__ u16 tile[64 * 72];
  const int t = threadIdx.x;
  if (blockIdx.x < 768) {                              // --- hid transpose (coalesced reads) ---
    const int b = blockIdx.x;
    const int kband = b & 3, q = (b >> 2) & 3, l = (b >> 4) % 3, head = b / 48;
    const int kl = t >> 2, rg = t & 3;                 // 4 threads per k-row, 16 cols each
    const float* src = W_hid + (((head*3 + l)*256 + kband*64 + kl) << 8) + q*64 + rg*16;
    u16* dt = &tile[kl*72 + rg*16];
#pragma unroll
    for (int m = 0; m < 4; ++m) {
      float4 v = *(const float4*)(src + m*4);
      ushort4 o; o.x = f2b(v.x); o.y = f2b(v.y); o.z = f2b(v.z); o.w = f2b(v.w);
      *(ushort4*)(dt + m*4) = o;
    }
    __syncthreads();
    u16* lbase = ws + head*HEAD_WS + HID_OFF + l*HID_ELS;
#pragma unroll
    for (int p = 0; p < 2; ++p) {
      const int idx = t + p*256;                        // [0,512): cl = idx>>6, rq = idx&63
      const int cl = idx >> 6, rq = idx & 63;
      const int nn = q*64 + rq, cc = kband*8 + cl;
      const int klc = (cl ^ (rq & 7)) * 8;              // source chunk within band (XOR swizzle)
      u16 v8[8];
#pragma unroll
      for (int j = 0; j < 8; ++j) v8[j] = tile[(klc + j)*72 + rq];
      uint4 o;
      o.x = (u32)v8[0] | ((u32)v8[1] << 16); o.y = (u32)v8[2] | ((u32)v8[3] << 16);
      o.z = (u32)v8[4] | ((u32)v8[5] << 16); o.w = (u32)v8[6] | ((u32)v8[7] << 16);
      *(uint4*)(lbase + (nn << 8) + cc*8) = o;          // row-major 256, XOR-chunked
    }
    return;
  }
  if (blockIdx.x >= 944) {                             // --- coords passthrough ---
    const int i = (blockIdx.x - 944) * 256 + t;        // 512 x 256 = 131072 uint4
    cdst[i] = csrc[i];
    return;
  }
  // --- L0 (bias folded @k=40) + OUT images ---
  const int r = (blockIdx.x - 768) * 256 + t;          // 176 blocks -> 45056 = 16 x 2816
  const int head = r / 2816, f = r % 2816;
  u16 v[8]; int dst;
  if (f < 1792) {                                      // L0: rows nn x 56
    const int nn = f / 7, k0 = (f % 7) * 8;
#pragma unroll
    for (int j = 0; j < 8; ++j) {
      const int k = k0 + j;
      v[j] = (k < 40) ? f2b(W_in[head*10240 + (k << 8) + nn])
           : (k == 40) ? f2b(b_in[(head << 8) + nn]) : (u16)0;
    }
    dst = head*HEAD_WS + nn*56 + k0;
  } else {                                             // OUT: 32 rows x 32 chunks, XOR
    const int f2 = f - 1792;
    const int nn = f2 >> 5, cc = f2 & 31, kb = 8 * (cc ^ (nn & 7));
#pragma unroll
    for (int j = 0; j < 8; ++j)
      v[j] = (nn < 3) ? f2b(W_out[head*768 + (kb + j)*3 + nn]) : (u16)0;
    dst = head*HEAD_WS + OUT_OFF + (nn << 8) + cc*8;
  }
  uint4 o;
  o.x = (u32)v[0] | ((u32)v[1] << 16); o.y = (u32)v[2] | ((u32)v[3] << 16);
  o.z = (u32)v[4] | ((u32)v[5] << 16); o.w = (u32)v[6] | ((u32)v[7] << 16);
  *(uint4*)(ws + dst) = o;
}

// ---------------- main fused MLP: 512 thr (8 waves), 32 pts/wave, 2x32KB ring (R3 structure) ----------------
__launch_bounds__(512, 2)
__global__ void mlp_main(const float* __restrict__ coords, const int* __restrict__ head_idx,
                         const float* __restrict__ b_hid, const float* __restrict__ b_out,
                         const u16* __restrict__ ws, float* __restrict__ out) {
  __shared__ short ring[2 * 16384];                    // 2 x 32 KB weight-quarter slots
  const int tid = threadIdx.x;
  const int lane = tid & 63, wv = tid >> 6;
  const int n = lane & 31, hh = lane >> 5;
  const int head = blockIdx.x & 15, chunk = blockIdx.x >> 4;
  const u16* wsh = ws + head * HEAD_WS;
  const u16* hb  = wsh + HID_OFF;

  stage_now(wsh + 0*3584, ring,          7168, tid);   // L0 q0 -> slot0
  stage_now(wsh + 1*3584, ring + 16384,  7168, tid);   // L0 q1 -> slot1

  // gather + positional encoding (B-layout: lane = point, k = 16t + 8*hh + j)
  const int pt = chunk*256 + wv*32 + n;
  const int g  = head_idx[head*CAP + pt];
  const float2 cxy = *(const float2*)(coords + 2*g);
  const float xs = cxy.x, ys = cxy.y;
  const float bo0 = b_out[head*3+0], bo1 = b_out[head*3+1], bo2 = b_out[head*3+2];

  F8 pe[3];
#pragma unroll
  for (int t = 0; t < 3; ++t) {
    float e[8];
#pragma unroll
    for (int half = 0; half < 2; ++half) {
      const int l = 4*t + 2*hh + half;                 // k = 4l + comp: sinx,siny,cosx,cosy
      if (l < 10) {
        const float fr = 3.14159265358979323846f * (float)(1 << l);
        float s1, c1, s2, c2;
        sincosf(xs * fr, &s1, &c1);
        sincosf(ys * fr, &s2, &c2);
        e[4*half+0] = s1; e[4*half+1] = s2; e[4*half+2] = c1; e[4*half+3] = c2;
      } else {
        e[4*half+0] = (l == 10) ? 1.0f : 0.0f;         // k=40 -> folded bias channel
        e[4*half+1] = 0.f; e[4*half+2] = 0.f; e[4*half+3] = 0.f;
      }
    }
    pe[t].u[0] = packbf2(e[0], e[1]); pe[t].u[1] = packbf2(e[2], e[3]);
    pe[t].u[2] = packbf2(e[4], e[5]); pe[t].u[3] = packbf2(e[6], e[7]);
  }

  F8 act0[16], act1[16];
  __syncthreads();                                     // L0 q0/q1 staged

  // ===== layer 0: pe -> act0 (K=48, bias folded) =====
#pragma unroll
  for (int rp = 0; rp < 4; ++rp) {
    short* sl = ring + (rp & 1) * 16384;
    const u16* src = (rp < 2) ? (wsh + (rp + 2)*3584) : (hb + (rp - 2)*16384);
    const int bytes = (rp < 2) ? 7168 : 32768;
    uint4 st[4];
    stage_ld(src, bytes, tid, st);                     // hoisted: VMEM hides under MFMA+barrier
    f32x16 acc0 = (f32x16)0.f, acc1 = (f32x16)0.f;
#pragma unroll
    for (int t = 0; t < 3; ++t) {
      acc0 = mfma16(fragL0(sl, 0, t, n, hh), pe[t].v, acc0);
      acc1 = mfma16(fragL0(sl, 1, t, n, hh), pe[t].v, acc1);
    }
    __syncthreads();
    epilogue(acc0, hh, act0[4*rp+0], act0[4*rp+1]);
    epilogue(acc1, hh, act0[4*rp+2], act0[4*rp+3]);
    stage_st(sl, bytes, tid, st);                      // drained by next barrier
  }

  // ===== hidden layers (bias as acc-init, prefetched one phase ahead) =====
  auto hid_layer = [&](const float* bias, F8 (&ain)[16], F8 (&aout)[16],
                       const u16* j0, const u16* j1, const u16* j2, const u16* j3,
                       int b2, int b3) {
    float4 bc0[4], bc1[4], bn0[4], bn1[4];
    load_bias_raw(bias, 0, hh, bc0); load_bias_raw(bias, 1, hh, bc1);
    const u16* jsrc[4] = { j0, j1, j2, j3 };
    const int  jb[4]   = { 32768, 32768, b2, b3 };
#pragma unroll
    for (int rp = 0; rp < 4; ++rp) {
      short* sl = ring + (rp & 1) * 16384;
      if (rp < 3) { load_bias_raw(bias, 2*rp+2, hh, bn0); load_bias_raw(bias, 2*rp+3, hh, bn1); }
      uint4 st[4];
      if (jb[rp] > 0) stage_ld(jsrc[rp], jb[rp], tid, st);   // hoisted
      f32x16 acc0 = bias_to_acc(bc0);
      f32x16 acc1 = bias_to_acc(bc1);
#pragma unroll
      for (int t = 0; t < 16; ++t) {
        bf16x8 a0 = fragH(sl, 0, t, n, hh);
        bf16x8 a1 = fragH(sl, 1, t, n, hh);
        acc0 = mfma16(a0, ain[t].v, acc0);
        acc1 = mfma16(a1, ain[t].v, acc1);
      }
      __syncthreads();                                 // all waves done with this quarter
      epilogue(acc0, hh, aout[4*rp+0], aout[4*rp+1]);
      epilogue(acc1, hh, aout[4*rp+2], aout[4*rp+3]);
      if (jb[rp] > 0) stage_st(sl, jb[rp], tid, st);   // refill freed slot
      if (rp < 3) {
#pragma unroll
        for (int q = 0; q < 4; ++q) { bc0[q] = bn0[q]; bc1[q] = bn1[q]; }
      }
    }
  };

  hid_layer(b_hid + (head*3+0)*256, act0, act1,
            hb + 2*16384, hb + 3*16384, hb + HID_ELS, hb + HID_ELS + 16384, 32768, 32768);
  hid_layer(b_hid + (head*3+1)*256, act1, act0,
            hb + HID_ELS + 2*16384, hb + HID_ELS + 3*16384,
            hb + 2*HID_ELS, hb + 2*HID_ELS + 16384, 32768, 32768);
  hid_layer(b_hid + (head*3+2)*256, act0, act1,
            hb + 2*HID_ELS + 2*16384, hb + 2*HID_ELS + 3*16384,
            wsh + OUT_OFF, (const u16*)0, 16384, 0);

  // ===== out layer: act1 x W_out^T (32-row image in slot0), scatter =====
  f32x16 acc = (f32x16)0.f;
#pragma unroll
  for (int t = 0; t < 16; ++t)
    acc = mfma16(fragH(ring, 0, t, n, hh), act1[t].v, acc);
  if (hh == 0) {                                       // rows 0..2 live in hh=0 regs 0..2
    const long base = (long)g * 3;
    out[base + 0] = acc[0] + bo0;
    out[base + 1] = acc[1] + bo1;
    out[base + 2] = acc[2] + bo2;
  }
}

extern "C" void kernel_launch(void* const* d_in, const int* in_sizes, int n_in,
                              void* d_out, int out_size, void* d_ws, size_t ws_size,
                              hipStream_t stream) {
  const float* coords   = (const float*)d_in[0];
  const int*   head_idx = (const int*)d_in[1];
  const float* W_in     = (const float*)d_in[2];
  const float* b_in     = (const float*)d_in[3];
  const float* W_hid    = (const float*)d_in[4];
  const float* b_hid    = (const float*)d_in[5];
  const float* W_out    = (const float*)d_in[6];
  const float* b_out    = (const float*)d_in[7];
  float* out = (float*)d_out;
  u16*   ws  = (u16*)d_ws;
  if (ws_size < (size_t)HEAD_WS * 16 * sizeof(u16)) return;

  prep<<<dim3(1456), dim3(256), 0, stream>>>(W_in, b_in, W_hid, b_in, W_out, ws,
                                             (const uint4*)coords, (uint4*)(out + 786432));
  mlp_main<<<dim3(1024), dim3(512), 0, stream>>>(coords, head_idx, b_hid, b_out, ws, out);
}